// Round 5
// baseline (14433.864 us; speedup 1.0000x reference)
//
#include <hip/hip_runtime.h>

// RnnTagger (f32 in / f32 out): tokens[64*512] i32; emb[50000,256]; W_ih[1536,256];
// W_hh[1536,512]; b_ih[1536]; b_hh[1536]; W_tag[64,512]; b_tag[64].
// d_out f32: tag_logits [64,512,64] then preds [64,512] flat.
//
// f32-faithful MFMA via f16 double-split: x ~= hi + lo/4096 (hi,lo f16); product
// = 3 f16 MFMAs (m += Ah*Wh; s += Al*Wh + Ah*Wl; result = m + s/4096).
//
// R5 sync (replaces R3's threadfence barrier, R4's counter): each h element is a
// self-tagged 8B atom {lo32: pk = f16hi | f16lo<<16; hi32: tag = step}. Producer
// at step t atomically stores {pk, t+1} into buf[(t+1)&1]; consumer at step t
// retry-loads buf[t&1] until tag==t. Data+tag in one atom -> no ordering
// assumptions, no fences, no counter. Tag-success proves all waves finished
// step t-1, so the double buffer is race-free.
//
// ws (72,482,816 B):
//   [0,+524288)         h tagged dbuf  u64[2][64][512]
//   [524288,+3145728)   whh2  [hi/lo][1536][512] f16
//   [3670016,+1572864)  wih2  [hi/lo][1536][256] f16
//   [5242880,+131072)   wtag2 [hi/lo][64][512] f16
//   [5373952,+67108864) st    [b*512+t][512] f32

typedef unsigned short ushortT;
typedef unsigned long long u64c;
typedef float f32x4 __attribute__((ext_vector_type(4)));
typedef _Float16 f16x8 __attribute__((ext_vector_type(8)));
typedef unsigned int u32x4 __attribute__((ext_vector_type(4)));

#define MFMAH(a, b, c) __builtin_amdgcn_mfma_f32_16x16x32_f16((a), (b), (c), 0, 0, 0)
#define KSC (1.0f / 4096.0f)

__device__ __forceinline__ void splitf(float x, ushortT& hi, ushortT& lo) {
    _Float16 h = (_Float16)x;
    float r = x - (float)h;
    _Float16 l = (_Float16)(r * 4096.0f);
    hi = __builtin_bit_cast(ushortT, h);
    lo = __builtin_bit_cast(ushortT, l);
}

// ---------- k0: split weights into f16 hi/lo planes ----------
__global__ __launch_bounds__(256) void split_weights(
    const float* __restrict__ Whh, const float* __restrict__ Wih,
    const float* __restrict__ Wtag, ushortT* __restrict__ wh2,
    ushortT* __restrict__ wi2, ushortT* __restrict__ wt2)
{
    const int i = blockIdx.x * 256 + threadIdx.x;
    ushortT hi, lo;
    if (i < 786432) {                       // 1536*512
        splitf(Whh[i], hi, lo);
        wh2[i] = hi; wh2[786432 + i] = lo;
    } else if (i < 786432 + 393216) {       // 1536*256
        const int j = i - 786432;
        splitf(Wih[j], hi, lo);
        wi2[j] = hi; wi2[393216 + j] = lo;
    } else if (i < 786432 + 393216 + 32768) {   // 64*512
        const int j = i - 786432 - 393216;
        splitf(Wtag[j], hi, lo);
        wt2[j] = hi; wt2[32768 + j] = lo;
    }
}

// ---------- k1: zero tagged h double buffer (tag 0 == "state after step -1") ----------
__global__ void init_ws(uint4* p) {
    int i = blockIdx.x * blockDim.x + threadIdx.x;
    if (i < 32768) {   // 524288 B / 16
        uint4 z; z.x = 0u; z.y = 0u; z.z = 0u; z.w = 0u;
        p[i] = z;
    }
}

// ---------- k2: fused gi + serial GRU recurrence ----------
// 32 WGs x 256. cluster = bid>>3 owns batch rows [cluster*16,+16); jg = bid&7
// owns h-cols [jg*64,+64); wave owns 16 cols (all 3 gates).
__global__ __launch_bounds__(256, 1) void gru_rec(
    const int* __restrict__ tok, const float* __restrict__ emb,
    const ushortT* __restrict__ wih2, const ushortT* __restrict__ whh2,
    const float* __restrict__ bih, const float* __restrict__ bhh,
    u64c* __restrict__ hbt, float* __restrict__ st)
{
    __shared__ ushortT xl[2][2][16][264];   // x dbuf: [buf][hi/lo][16 b][256k pad 264]

    const int bid = blockIdx.x;
    const int cluster = bid >> 3;
    const int jg = bid & 7;
    const int tid = threadIdx.x;
    const int wave = tid >> 6;
    const int lane = tid & 63;
    const int ln = lane & 15, quad = lane >> 4;
    const int m0 = cluster * 16;
    const int j_lane = jg * 64 + wave * 16 + ln;

    // Preload W_hh hi fragments (static): 48 frags.
    f16x8 Bh[3][16];
#pragma unroll
    for (int g = 0; g < 3; ++g) {
        const ushortT* wrow = whh2 + (size_t)(g * 512 + j_lane) * 512;
#pragma unroll
        for (int ks = 0; ks < 16; ++ks)
            Bh[g][ks] = *reinterpret_cast<const f16x8*>(wrow + ks * 32 + quad * 8);
    }
    const float c_r  = bih[j_lane]        + bhh[j_lane];
    const float c_z  = bih[512 + j_lane]  + bhh[512 + j_lane];
    const float bi_n = bih[1024 + j_lane];
    const float bh_n = bhh[1024 + j_lane];

    // Prologue: stage x_0 (split f16 hi/lo) into LDS buf 0.
    {
        const int r = tid >> 4, c0 = (tid & 15) * 16;
        const int token = tok[(m0 + r) * 512];
        const float* xsrc = emb + (size_t)token * 256 + c0;
#pragma unroll
        for (int i = 0; i < 16; ++i) {
            ushortT hi, lo; splitf(xsrc[i], hi, lo);
            xl[0][0][r][c0 + i] = hi; xl[0][1][r][c0 + i] = lo;
        }
    }
    __syncthreads();

    float hprev[4] = {0.f, 0.f, 0.f, 0.f};

    for (int t = 0; t < 512; ++t) {
        const int rb = t & 1;
        const int wb = rb ^ 1;

        // (a) prefetch x_{t+1} into other LDS buffer (plain, as R3)
        {
            const int r = tid >> 4, c0 = (tid & 15) * 16;
            const int tp = (t + 1) & 511;
            const int token = tok[(m0 + r) * 512 + tp];
            const float* xsrc = emb + (size_t)token * 256 + c0;
#pragma unroll
            for (int i = 0; i < 16; ++i) {
                ushortT hi, lo; splitf(xsrc[i], hi, lo);
                xl[wb][0][r][c0 + i] = hi; xl[wb][1][r][c0 + i] = lo;
            }
        }

        // accumulators: r,z combine gi+gh; n kept separate (needs r * gh_n)
        f32x4 m_r = (f32x4){0.f,0.f,0.f,0.f}, s_r = (f32x4){0.f,0.f,0.f,0.f};
        f32x4 m_z = (f32x4){0.f,0.f,0.f,0.f}, s_z = (f32x4){0.f,0.f,0.f,0.f};
        f32x4 m_gin = (f32x4){0.f,0.f,0.f,0.f}, s_gin = (f32x4){0.f,0.f,0.f,0.f};
        f32x4 m_ghn = (f32x4){0.f,0.f,0.f,0.f}, s_ghn = (f32x4){0.f,0.f,0.f,0.f};

        // (b) gi = x_t @ W_ih^T  (f16-split; W_ih/L2; runs before h is ready)
#pragma unroll
        for (int ks = 0; ks < 8; ++ks) {
            const int k = ks * 32 + quad * 8;
            f16x8 Axh = *reinterpret_cast<const f16x8*>(&xl[rb][0][ln][k]);
            f16x8 Axl = *reinterpret_cast<const f16x8*>(&xl[rb][1][ln][k]);
#pragma unroll
            for (int g = 0; g < 3; ++g) {
                const ushortT* wr = wih2 + (size_t)(g * 512 + j_lane) * 256 + k;
                f16x8 Wh = *reinterpret_cast<const f16x8*>(wr);
                f16x8 Wl = *reinterpret_cast<const f16x8*>(wr + 393216);
                if (g == 0) {
                    m_r = MFMAH(Axh, Wh, m_r);
                    s_r = MFMAH(Axl, Wh, s_r);
                    s_r = MFMAH(Axh, Wl, s_r);
                } else if (g == 1) {
                    m_z = MFMAH(Axh, Wh, m_z);
                    s_z = MFMAH(Axl, Wh, s_z);
                    s_z = MFMAH(Axh, Wl, s_z);
                } else {
                    m_gin = MFMAH(Axh, Wh, m_gin);
                    s_gin = MFMAH(Axl, Wh, s_gin);
                    s_gin = MFMAH(Axh, Wl, s_gin);
                }
            }
        }

        // (c) tagged consume of h_{t-1} + gh MFMA, 8 batches of 2 K-chunks,
        //     depth-2 prefetch. The tag-retry loop IS the cluster barrier.
        u64c* abase = hbt + (size_t)rb * 32768 + (m0 + ln) * 512;
        const unsigned etag = (unsigned)t;
        u64c e[2][16];
#pragma unroll
        for (int c = 0; c < 2; ++c)
#pragma unroll
            for (int i = 0; i < 8; ++i) {
                e[0][c*8+i] = __hip_atomic_load(abase + c*32 + quad*8 + i,
                                                __ATOMIC_RELAXED, __HIP_MEMORY_SCOPE_AGENT);
                e[1][c*8+i] = __hip_atomic_load(abase + (2+c)*32 + quad*8 + i,
                                                __ATOMIC_RELAXED, __HIP_MEMORY_SCOPE_AGENT);
            }

        for (int bt = 0; bt < 8; ++bt) {
            u64c* cur = e[bt & 1];
            // retry until all 16 tags == t (per-lane)
            for (;;) {
                bool ok = true;
#pragma unroll
                for (int i = 0; i < 16; ++i) ok &= ((unsigned)(cur[i] >> 32) == etag);
                if (ok) break;
#pragma unroll
                for (int c = 0; c < 2; ++c)
#pragma unroll
                    for (int i = 0; i < 8; ++i)
                        cur[c*8+i] = __hip_atomic_load(abase + (bt*2+c)*32 + quad*8 + i,
                                                       __ATOMIC_RELAXED, __HIP_MEMORY_SCOPE_AGENT);
            }
            // extract Ah/Al for the 2 chunks before cur is re-used for prefetch
            f16x8 AH[2], AL[2];
#pragma unroll
            for (int c = 0; c < 2; ++c) {
                u32x4 ah, al;
#pragma unroll
                for (int i = 0; i < 4; ++i) {
                    const unsigned p0 = (unsigned)cur[c*8 + 2*i];
                    const unsigned p1 = (unsigned)cur[c*8 + 2*i + 1];
                    ah[i] = (p0 & 0xffffu) | (p1 << 16);
                    al[i] = (p0 >> 16) | (p1 & 0xffff0000u);
                }
                AH[c] = __builtin_bit_cast(f16x8, ah);
                AL[c] = __builtin_bit_cast(f16x8, al);
            }
            if (bt < 6) {   // prefetch batch bt+2 into this slot
#pragma unroll
                for (int c = 0; c < 2; ++c)
#pragma unroll
                    for (int i = 0; i < 8; ++i)
                        cur[c*8+i] = __hip_atomic_load(abase + ((bt+2)*2+c)*32 + quad*8 + i,
                                                       __ATOMIC_RELAXED, __HIP_MEMORY_SCOPE_AGENT);
            }
            // gh MFMAs for chunks 2bt, 2bt+1
#pragma unroll
            for (int c = 0; c < 2; ++c) {
                const int ck = bt * 2 + c;
                const int k = ck * 32 + quad * 8;
#pragma unroll
                for (int g = 0; g < 3; ++g) {
                    f16x8 Wl = *reinterpret_cast<const f16x8*>(
                        whh2 + 786432 + (size_t)(g * 512 + j_lane) * 512 + k);
                    if (g == 0) {
                        m_r = MFMAH(AH[c], Bh[0][ck], m_r);
                        s_r = MFMAH(AL[c], Bh[0][ck], s_r);
                        s_r = MFMAH(AH[c], Wl, s_r);
                    } else if (g == 1) {
                        m_z = MFMAH(AH[c], Bh[1][ck], m_z);
                        s_z = MFMAH(AL[c], Bh[1][ck], s_z);
                        s_z = MFMAH(AH[c], Wl, s_z);
                    } else {
                        m_ghn = MFMAH(AH[c], Bh[2][ck], m_ghn);
                        s_ghn = MFMAH(AL[c], Bh[2][ck], s_ghn);
                        s_ghn = MFMAH(AH[c], Wl, s_ghn);
                    }
                }
            }
        }

        // (e) gates (f32) + h_new; tagged 8B atomic h store + plain f32 state
        u64c* hw = hbt + (size_t)wb * 32768;
        const u64c ntag = ((u64c)(unsigned)(t + 1)) << 32;
#pragma unroll
        for (int r4 = 0; r4 < 4; ++r4) {
            const float pre_r = m_r[r4] + s_r[r4] * KSC + c_r;
            const float pre_z = m_z[r4] + s_z[r4] * KSC + c_z;
            const float gin   = m_gin[r4] + s_gin[r4] * KSC + bi_n;
            const float ghn   = m_ghn[r4] + s_ghn[r4] * KSC + bh_n;
            const float rr = 1.f / (1.f + expf(-pre_r));
            const float zz = 1.f / (1.f + expf(-pre_z));
            const float nn = tanhf(gin + rr * ghn);
            const float hn = (1.f - zz) * nn + zz * hprev[r4];
            hprev[r4] = hn;
            ushortT hi, lo; splitf(hn, hi, lo);
            const unsigned pk = (unsigned)hi | ((unsigned)lo << 16);
            const int b = m0 + quad * 4 + r4;
            __hip_atomic_store(&hw[b * 512 + j_lane], ntag | (u64c)pk,
                               __ATOMIC_RELAXED, __HIP_MEMORY_SCOPE_AGENT);
            st[((size_t)b * 512 + t) * 512 + j_lane] = hn;
        }

        __syncthreads();   // xl buffer turnover
    }
}

// ---------- k3: tag logits + argmax + PAD mask (R3-identical) ----------
__global__ __launch_bounds__(256) void tag_argmax(
    const float* __restrict__ st, const ushortT* __restrict__ wtag2,
    const float* __restrict__ btag, const int* __restrict__ tok,
    float* __restrict__ out)
{
    const int wave = threadIdx.x >> 6;
    const int lane = threadIdx.x & 63;
    const int ln = lane & 15, quad = lane >> 4;
    const int mt = blockIdx.x * 4 + wave;   // 0..2047

    const float* arow = st + (size_t)(mt * 16 + ln) * 512;
    f32x4 am[4], as_[4];
#pragma unroll
    for (int ti = 0; ti < 4; ++ti) { am[ti] = (f32x4){0.f,0.f,0.f,0.f}; as_[ti] = (f32x4){0.f,0.f,0.f,0.f}; }

#pragma unroll
    for (int ks = 0; ks < 16; ++ks) {
        const int k = ks * 32 + quad * 8;
        f16x8 Ah, Al;
#pragma unroll
        for (int e = 0; e < 8; ++e) {
            const float x = arow[k + e];
            _Float16 h = (_Float16)x;
            Ah[e] = h;
            Al[e] = (_Float16)((x - (float)h) * 4096.0f);
        }
#pragma unroll
        for (int ti = 0; ti < 4; ++ti) {
            const ushortT* wr = wtag2 + (size_t)(ti * 16 + ln) * 512 + k;
            f16x8 Wh = *reinterpret_cast<const f16x8*>(wr);
            f16x8 Wl = *reinterpret_cast<const f16x8*>(wr + 32768);
            am[ti]  = MFMAH(Ah, Wh, am[ti]);
            as_[ti] = MFMAH(Ah, Wl, as_[ti]);
            as_[ti] = MFMAH(Al, Wh, as_[ti]);
        }
    }

    float vals[4][4];
#pragma unroll
    for (int ti = 0; ti < 4; ++ti) {
        const float bb = btag[ti * 16 + ln];
#pragma unroll
        for (int r = 0; r < 4; ++r) vals[ti][r] = am[ti][r] + as_[ti][r] * KSC + bb;
    }
#pragma unroll
    for (int ti = 0; ti < 4; ++ti)
#pragma unroll
        for (int r = 0; r < 4; ++r) {
            const int row = mt * 16 + quad * 4 + r;
            out[(size_t)row * 64 + ti * 16 + ln] = vals[ti][r];
        }
#pragma unroll
    for (int r = 0; r < 4; ++r) {
        float best = vals[0][r];
        int bc = ln;
#pragma unroll
        for (int ti = 1; ti < 4; ++ti) {
            const float v = vals[ti][r];
            const int c = ti * 16 + ln;
            if (v > best) { best = v; bc = c; }
        }
        for (int off = 1; off < 16; off <<= 1) {
            const float ov = __shfl_xor(best, off);
            const int oc = __shfl_xor(bc, off);
            if (ov > best || (ov == best && oc < bc)) { best = ov; bc = oc; }
        }
        if (ln == 0) {
            const int row = mt * 16 + quad * 4 + r;   // = b*512+t = token idx
            const int token = tok[row];
            const int pred = (token != 0) ? bc : 0;
            out[2097152 + (size_t)row] = (float)pred;
        }
    }
}

extern "C" void kernel_launch(void* const* d_in, const int* in_sizes, int n_in,
                              void* d_out, int out_size, void* d_ws, size_t ws_size,
                              hipStream_t stream) {
    const int*   tokens = (const int*)d_in[0];
    const float* emb    = (const float*)d_in[1];
    const float* Wih    = (const float*)d_in[2];
    const float* Whh    = (const float*)d_in[3];
    const float* bih    = (const float*)d_in[4];
    const float* bhh    = (const float*)d_in[5];
    const float* Wtag   = (const float*)d_in[6];
    const float* btag   = (const float*)d_in[7];

    char* ws = (char*)d_ws;
    u64c*     hbt   = (u64c*)ws;                     // 524,288 B
    ushortT*  whh2  = (ushortT*)(ws + 524288);       // 3,145,728 B
    ushortT*  wih2  = (ushortT*)(ws + 3670016);      // 1,572,864 B
    ushortT*  wtag2 = (ushortT*)(ws + 5242880);      // 131,072 B
    float*    stf   = (float*)(ws + 5373952);        // 67,108,864 B (total 72.48 MB)
    float*    out   = (float*)d_out;

    split_weights<<<4736, 256, 0, stream>>>(Whh, Wih, Wtag, whh2, wih2, wtag2);
    init_ws<<<128, 256, 0, stream>>>((uint4*)ws);
    gru_rec<<<32, 256, 0, stream>>>(tokens, emb, wih2, whh2, bih, bhh, hbt, stf);
    tag_argmax<<<512, 256, 0, stream>>>(stf, wtag2, btag, tokens, out);
}

// Round 6
// 8804.258 us; speedup vs baseline: 1.6394x; 1.6394x over previous
//
#include <hip/hip_runtime.h>

// RnnTagger (f32 in / f32 out): tokens[64*512] i32; emb[50000,256]; W_ih[1536,256];
// W_hh[1536,512]; b_ih[1536]; b_hh[1536]; W_tag[64,512]; b_tag[64].
// d_out f32: tag_logits [64,512,64] then preds [64,512] flat.
//
// f32-faithful MFMA via f16 double-split: x ~= hi + lo/4096 (hi,lo f16); product
// = 3 f16 MFMAs (m += Ah*Wh; s += Al*Wh + Ah*Wl; result = m + s/4096).
//
// Sync = R5's self-tagged 8B atoms {pk, step-tag} (passed correctness), but R6
// fixes R5's congestion collapse (657 MB FETCH, 28 us/step, MfmaUtil 0.6%):
//  - cooperative consume: 256 threads load the 8192-atom h tile ONCE (32/thread,
//    coalesced), publish pk to LDS; all 4 waves read A-frags from LDS (4x less
//    coherent traffic than R5's per-wave full-tile loads)
//  - s_sleep(2) backoff between tag-retry rounds (R5 had none -> fabric storm)
//  - W_hh hi plane streamed from L2 (frees 192 VGPRs for the 32 in-flight atoms)
//  - tagged h stores issued before st stores in the epilogue
//
// ws (72,482,816 B, same layout as R5):
//   [0,+524288)         h tagged dbuf  u64[2][64][512]
//   [524288,+3145728)   whh2  [hi/lo][1536][512] f16
//   [3670016,+1572864)  wih2  [hi/lo][1536][256] f16
//   [5242880,+131072)   wtag2 [hi/lo][64][512] f16
//   [5373952,+67108864) st    [b*512+t][512] f32

typedef unsigned short ushortT;
typedef unsigned long long u64c;
typedef float f32x4 __attribute__((ext_vector_type(4)));
typedef _Float16 f16x8 __attribute__((ext_vector_type(8)));
typedef unsigned int u32x4 __attribute__((ext_vector_type(4)));

#define MFMAH(a, b, c) __builtin_amdgcn_mfma_f32_16x16x32_f16((a), (b), (c), 0, 0, 0)
#define KSC (1.0f / 4096.0f)

__device__ __forceinline__ void splitf(float x, ushortT& hi, ushortT& lo) {
    _Float16 h = (_Float16)x;
    float r = x - (float)h;
    _Float16 l = (_Float16)(r * 4096.0f);
    hi = __builtin_bit_cast(ushortT, h);
    lo = __builtin_bit_cast(ushortT, l);
}

// ---------- k0: split weights into f16 hi/lo planes ----------
__global__ __launch_bounds__(256) void split_weights(
    const float* __restrict__ Whh, const float* __restrict__ Wih,
    const float* __restrict__ Wtag, ushortT* __restrict__ wh2,
    ushortT* __restrict__ wi2, ushortT* __restrict__ wt2)
{
    const int i = blockIdx.x * 256 + threadIdx.x;
    ushortT hi, lo;
    if (i < 786432) {                       // 1536*512
        splitf(Whh[i], hi, lo);
        wh2[i] = hi; wh2[786432 + i] = lo;
    } else if (i < 786432 + 393216) {       // 1536*256
        const int j = i - 786432;
        splitf(Wih[j], hi, lo);
        wi2[j] = hi; wi2[393216 + j] = lo;
    } else if (i < 786432 + 393216 + 32768) {   // 64*512
        const int j = i - 786432 - 393216;
        splitf(Wtag[j], hi, lo);
        wt2[j] = hi; wt2[32768 + j] = lo;
    }
}

// ---------- k1: zero tagged h double buffer (tag 0 = "after step -1") ----------
__global__ void init_ws(uint4* p) {
    int i = blockIdx.x * blockDim.x + threadIdx.x;
    if (i < 32768) {   // 524288 B / 16
        uint4 z; z.x = 0u; z.y = 0u; z.z = 0u; z.w = 0u;
        p[i] = z;
    }
}

// ---------- k2: fused gi + serial GRU recurrence ----------
// 32 WGs x 256. cluster = bid>>3 owns batch rows [cluster*16,+16); jg = bid&7
// owns h-cols [jg*64,+64); wave owns 16 cols (all 3 gates).
__global__ __launch_bounds__(256, 1) void gru_rec(
    const int* __restrict__ tok, const float* __restrict__ emb,
    const ushortT* __restrict__ wih2, const ushortT* __restrict__ whh2,
    const float* __restrict__ bih, const float* __restrict__ bhh,
    u64c* __restrict__ hbt, float* __restrict__ st)
{
    __shared__ ushortT xl[2][2][16][264];   // x dbuf: [buf][hi/lo][16 b][256k pad]
    __shared__ unsigned hl[8256];           // packed h tile [16 rows][512 + pad 4]

    const int bid = blockIdx.x;
    const int cluster = bid >> 3;
    const int jg = bid & 7;
    const int tid = threadIdx.x;
    const int wave = tid >> 6;
    const int lane = tid & 63;
    const int ln = lane & 15, quad = lane >> 4;
    const int m0 = cluster * 16;
    const int j_lane = jg * 64 + wave * 16 + ln;

    const float c_r  = bih[j_lane]        + bhh[j_lane];
    const float c_z  = bih[512 + j_lane]  + bhh[512 + j_lane];
    const float bi_n = bih[1024 + j_lane];
    const float bh_n = bhh[1024 + j_lane];

    // Prologue: stage x_0 (split f16 hi/lo) into LDS buf 0.
    const int xr = tid >> 4, xc = (tid & 15) * 16;
    {
        const int token = tok[(m0 + xr) * 512];
        const float* xsrc = emb + (size_t)token * 256 + xc;
#pragma unroll
        for (int i = 0; i < 16; ++i) {
            ushortT hi, lo; splitf(xsrc[i], hi, lo);
            xl[0][0][xr][xc + i] = hi; xl[0][1][xr][xc + i] = lo;
        }
    }
    __syncthreads();

    float hprev[4] = {0.f, 0.f, 0.f, 0.f};

    for (int t = 0; t < 512; ++t) {
        const int rb = t & 1;
        const int wb = rb ^ 1;
        u64c* tile = hbt + (size_t)rb * 32768 + (size_t)m0 * 512;

        // (A) cooperative tagged loads: 32 atoms/thread, coalesced, issued early
        u64c v[32];
#pragma unroll
        for (int j = 0; j < 32; ++j)
            v[j] = __hip_atomic_load(tile + tid + 256 * j,
                                     __ATOMIC_RELAXED, __HIP_MEMORY_SCOPE_AGENT);

        // (B) x_{t+1} global loads into regs (published to LDS in phase H)
        const int tp = (t + 1) & 511;
        const int xtoken = tok[(m0 + xr) * 512 + tp];
        const float* xsrc = emb + (size_t)xtoken * 256 + xc;
        f32x4 xv[4];
#pragma unroll
        for (int i = 0; i < 4; ++i)
            xv[i] = *reinterpret_cast<const f32x4*>(xsrc + i * 4);

        // accumulators: r,z combine gi+gh; n separate (needs r * gh_n)
        f32x4 m_r = (f32x4){0.f,0.f,0.f,0.f}, s_r = (f32x4){0.f,0.f,0.f,0.f};
        f32x4 m_z = (f32x4){0.f,0.f,0.f,0.f}, s_z = (f32x4){0.f,0.f,0.f,0.f};
        f32x4 m_gin = (f32x4){0.f,0.f,0.f,0.f}, s_gin = (f32x4){0.f,0.f,0.f,0.f};
        f32x4 m_ghn = (f32x4){0.f,0.f,0.f,0.f}, s_ghn = (f32x4){0.f,0.f,0.f,0.f};

        // (C) gi = x_t @ W_ih^T (overlaps the in-flight h loads)
#pragma unroll
        for (int ks = 0; ks < 8; ++ks) {
            const int k = ks * 32 + quad * 8;
            f16x8 Axh = *reinterpret_cast<const f16x8*>(&xl[rb][0][ln][k]);
            f16x8 Axl = *reinterpret_cast<const f16x8*>(&xl[rb][1][ln][k]);
#pragma unroll
            for (int g = 0; g < 3; ++g) {
                const ushortT* wr = wih2 + (size_t)(g * 512 + j_lane) * 256 + k;
                f16x8 Wh = *reinterpret_cast<const f16x8*>(wr);
                f16x8 Wl = *reinterpret_cast<const f16x8*>(wr + 393216);
                if (g == 0) {
                    m_r = MFMAH(Axh, Wh, m_r);
                    s_r = MFMAH(Axl, Wh, s_r);
                    s_r = MFMAH(Axh, Wl, s_r);
                } else if (g == 1) {
                    m_z = MFMAH(Axh, Wh, m_z);
                    s_z = MFMAH(Axl, Wh, s_z);
                    s_z = MFMAH(Axh, Wl, s_z);
                } else {
                    m_gin = MFMAH(Axh, Wh, m_gin);
                    s_gin = MFMAH(Axl, Wh, s_gin);
                    s_gin = MFMAH(Axh, Wl, s_gin);
                }
            }
        }

        // (D) tag check + retry with backoff (wave-uniform exit)
        const unsigned etag = (unsigned)t;
        for (;;) {
            bool ok = true;
#pragma unroll
            for (int j = 0; j < 32; ++j) ok &= ((unsigned)(v[j] >> 32) == etag);
            if (__all(ok)) break;
            __builtin_amdgcn_s_sleep(2);
#pragma unroll
            for (int j = 0; j < 32; ++j)
                v[j] = __hip_atomic_load(tile + tid + 256 * j,
                                         __ATOMIC_RELAXED, __HIP_MEMORY_SCOPE_AGENT);
        }

        // (E) publish packed payloads to LDS tile
#pragma unroll
        for (int j = 0; j < 32; ++j) {
            const int a = tid + 256 * j;
            hl[(a >> 9) * 516 + (a & 511)] = (unsigned)v[j];
        }
        __syncthreads();

        // (F) gh = h_{t-1} @ W_hh^T : A-frags from LDS, W streamed from L2
#pragma unroll
        for (int ks = 0; ks < 16; ++ks) {
            const int k = ks * 32 + quad * 8;
            const unsigned* hp = &hl[ln * 516 + k];
            u32x4 q0 = *reinterpret_cast<const u32x4*>(hp);
            u32x4 q1 = *reinterpret_cast<const u32x4*>(hp + 4);
            u32x4 ah, al;
#pragma unroll
            for (int i = 0; i < 2; ++i) {
                ah[i]   = (q0[2*i] & 0xffffu) | (q0[2*i+1] << 16);
                al[i]   = (q0[2*i] >> 16)     | (q0[2*i+1] & 0xffff0000u);
                ah[2+i] = (q1[2*i] & 0xffffu) | (q1[2*i+1] << 16);
                al[2+i] = (q1[2*i] >> 16)     | (q1[2*i+1] & 0xffff0000u);
            }
            f16x8 Ah = __builtin_bit_cast(f16x8, ah);
            f16x8 Al = __builtin_bit_cast(f16x8, al);
#pragma unroll
            for (int g = 0; g < 3; ++g) {
                const ushortT* wr = whh2 + (size_t)(g * 512 + j_lane) * 512 + k;
                f16x8 Wh = *reinterpret_cast<const f16x8*>(wr);
                f16x8 Wl = *reinterpret_cast<const f16x8*>(wr + 786432);
                if (g == 0) {
                    m_r = MFMAH(Ah, Wh, m_r);
                    s_r = MFMAH(Al, Wh, s_r);
                    s_r = MFMAH(Ah, Wl, s_r);
                } else if (g == 1) {
                    m_z = MFMAH(Ah, Wh, m_z);
                    s_z = MFMAH(Al, Wh, s_z);
                    s_z = MFMAH(Ah, Wl, s_z);
                } else {
                    m_ghn = MFMAH(Ah, Wh, m_ghn);
                    s_ghn = MFMAH(Al, Wh, s_ghn);
                    s_ghn = MFMAH(Ah, Wl, s_ghn);
                }
            }
        }

        // (G) gates + h_new; tagged h stores FIRST, st stores second
        u64c* hw = hbt + (size_t)wb * 32768;
        const u64c ntag = ((u64c)(unsigned)(t + 1)) << 32;
        float hn4[4];
#pragma unroll
        for (int r4 = 0; r4 < 4; ++r4) {
            const float pre_r = m_r[r4] + s_r[r4] * KSC + c_r;
            const float pre_z = m_z[r4] + s_z[r4] * KSC + c_z;
            const float gin   = m_gin[r4] + s_gin[r4] * KSC + bi_n;
            const float ghn   = m_ghn[r4] + s_ghn[r4] * KSC + bh_n;
            const float rr = 1.f / (1.f + expf(-pre_r));
            const float zz = 1.f / (1.f + expf(-pre_z));
            const float nn = tanhf(gin + rr * ghn);
            const float hn = (1.f - zz) * nn + zz * hprev[r4];
            hprev[r4] = hn;
            hn4[r4] = hn;
            ushortT hi, lo; splitf(hn, hi, lo);
            const unsigned pk = (unsigned)hi | ((unsigned)lo << 16);
            const int b = m0 + quad * 4 + r4;
            __hip_atomic_store(&hw[b * 512 + j_lane], ntag | (u64c)pk,
                               __ATOMIC_RELAXED, __HIP_MEMORY_SCOPE_AGENT);
        }
#pragma unroll
        for (int r4 = 0; r4 < 4; ++r4) {
            const int b = m0 + quad * 4 + r4;
            st[((size_t)b * 512 + t) * 512 + j_lane] = hn4[r4];
        }

        // (H) publish x_{t+1} into LDS buffer wb
#pragma unroll
        for (int i = 0; i < 16; ++i) {
            ushortT hi, lo; splitf(xv[i >> 2][i & 3], hi, lo);
            xl[wb][0][xr][xc + i] = hi; xl[wb][1][xr][xc + i] = lo;
        }
        __syncthreads();   // xl + hl turnover
    }
}

// ---------- k3: tag logits + argmax + PAD mask (R5-identical) ----------
__global__ __launch_bounds__(256) void tag_argmax(
    const float* __restrict__ st, const ushortT* __restrict__ wtag2,
    const float* __restrict__ btag, const int* __restrict__ tok,
    float* __restrict__ out)
{
    const int wave = threadIdx.x >> 6;
    const int lane = threadIdx.x & 63;
    const int ln = lane & 15, quad = lane >> 4;
    const int mt = blockIdx.x * 4 + wave;   // 0..2047

    const float* arow = st + (size_t)(mt * 16 + ln) * 512;
    f32x4 am[4], as_[4];
#pragma unroll
    for (int ti = 0; ti < 4; ++ti) { am[ti] = (f32x4){0.f,0.f,0.f,0.f}; as_[ti] = (f32x4){0.f,0.f,0.f,0.f}; }

#pragma unroll
    for (int ks = 0; ks < 16; ++ks) {
        const int k = ks * 32 + quad * 8;
        f16x8 Ah, Al;
#pragma unroll
        for (int e = 0; e < 8; ++e) {
            const float x = arow[k + e];
            _Float16 h = (_Float16)x;
            Ah[e] = h;
            Al[e] = (_Float16)((x - (float)h) * 4096.0f);
        }
#pragma unroll
        for (int ti = 0; ti < 4; ++ti) {
            const ushortT* wr = wtag2 + (size_t)(ti * 16 + ln) * 512 + k;
            f16x8 Wh = *reinterpret_cast<const f16x8*>(wr);
            f16x8 Wl = *reinterpret_cast<const f16x8*>(wr + 32768);
            am[ti]  = MFMAH(Ah, Wh, am[ti]);
            as_[ti] = MFMAH(Ah, Wl, as_[ti]);
            as_[ti] = MFMAH(Al, Wh, as_[ti]);
        }
    }

    float vals[4][4];
#pragma unroll
    for (int ti = 0; ti < 4; ++ti) {
        const float bb = btag[ti * 16 + ln];
#pragma unroll
        for (int r = 0; r < 4; ++r) vals[ti][r] = am[ti][r] + as_[ti][r] * KSC + bb;
    }
#pragma unroll
    for (int ti = 0; ti < 4; ++ti)
#pragma unroll
        for (int r = 0; r < 4; ++r) {
            const int row = mt * 16 + quad * 4 + r;
            out[(size_t)row * 64 + ti * 16 + ln] = vals[ti][r];
        }
#pragma unroll
    for (int r = 0; r < 4; ++r) {
        float best = vals[0][r];
        int bc = ln;
#pragma unroll
        for (int ti = 1; ti < 4; ++ti) {
            const float v = vals[ti][r];
            const int c = ti * 16 + ln;
            if (v > best) { best = v; bc = c; }
        }
        for (int off = 1; off < 16; off <<= 1) {
            const float ov = __shfl_xor(best, off);
            const int oc = __shfl_xor(bc, off);
            if (ov > best || (ov == best && oc < bc)) { best = ov; bc = oc; }
        }
        if (ln == 0) {
            const int row = mt * 16 + quad * 4 + r;   // = b*512+t = token idx
            const int token = tok[row];
            const int pred = (token != 0) ? bc : 0;
            out[2097152 + (size_t)row] = (float)pred;
        }
    }
}

extern "C" void kernel_launch(void* const* d_in, const int* in_sizes, int n_in,
                              void* d_out, int out_size, void* d_ws, size_t ws_size,
                              hipStream_t stream) {
    const int*   tokens = (const int*)d_in[0];
    const float* emb    = (const float*)d_in[1];
    const float* Wih    = (const float*)d_in[2];
    const float* Whh    = (const float*)d_in[3];
    const float* bih    = (const float*)d_in[4];
    const float* bhh    = (const float*)d_in[5];
    const float* Wtag   = (const float*)d_in[6];
    const float* btag   = (const float*)d_in[7];

    char* ws = (char*)d_ws;
    u64c*     hbt   = (u64c*)ws;                     // 524,288 B
    ushortT*  whh2  = (ushortT*)(ws + 524288);       // 3,145,728 B
    ushortT*  wih2  = (ushortT*)(ws + 3670016);      // 1,572,864 B
    ushortT*  wtag2 = (ushortT*)(ws + 5242880);      // 131,072 B
    float*    stf   = (float*)(ws + 5373952);        // 67,108,864 B (total 72.48 MB)
    float*    out   = (float*)d_out;

    split_weights<<<4736, 256, 0, stream>>>(Whh, Wih, Wtag, whh2, wih2, wtag2);
    init_ws<<<128, 256, 0, stream>>>((uint4*)ws);
    gru_rec<<<32, 256, 0, stream>>>(tokens, emb, wih2, whh2, bih, bhh, hbt, stf);
    tag_argmax<<<512, 256, 0, stream>>>(stf, wtag2, btag, tokens, out);
}